// Round 6
// baseline (8249.774 us; speedup 1.0000x reference)
//
#include <hip/hip_runtime.h>
#include <math.h>

// Problem dims
#define B_   256
#define T_   512
#define F_   64
#define H1_  100
#define H2_  128
#define OUT_ 19
#define G1_  400   // 4*H1
#define G2_  512   // 4*H2
#define TC   32    // timesteps per chunk
#define NCHUNK (T_/TC)

// ---- LDS layout (float indices) ----
// R1 region [0,16384):
//   phase A: xs[TC*F_]=2048 @0, xp1[TC*G1_]=12800 @2048 (ends 14848)
//   phase B: xp2[TC*G2_]=16384 @0
// H1C  [16384,19584): TC*H1_=3200
// WLDS [19584,40064): LDS-resident weight rows; U1 rows 80..99 (20x400=8000)
//                     during A1, U2 rows 88..127 (40x512=20480) during B
// ZBUF [40064,40576): 512
// H1S  [40576,40704): 128 (100 used)
// H2S  [40704,40832): 128
#define OFF_XS    0
#define OFF_XP1   (TC*F_)                 // 2048
#define OFF_XP2   0
#define OFF_H1C   16384
#define OFF_WLDS  (OFF_H1C + TC*H1_)      // 19584
#define OFF_ZBUF  (OFF_WLDS + 20480)      // 40064
#define OFF_H1S   (OFF_ZBUF + 512)        // 40576
#define OFF_H2S   (OFF_H1S + 128)         // 40704
#define LDS_FLOATS (OFF_H2S + 128)        // 40832 floats = 163328 B (<=163840)

#define U1_REG_ROWS 80    // rows 0..79 in regs (20 f4), 80..99 in LDS (20 rows)
#define U2_REG_ROWS 88    // rows 0..87 in regs (22 f4), 88..127 in LDS (40 rows)

__device__ __forceinline__ float sigm(float x) {
    return 1.0f / (1.0f + __expf(-x));
}

// Named float4 locals (never >22 live) — max weight regs 88, total ~115 < 128 grant.
#define REP5(M)  M(0) M(1) M(2) M(3) M(4)
#define REP16(M) REP5(M) M(5) M(6) M(7) M(8) M(9) M(10) M(11) M(12) M(13) M(14) M(15)
#define REP20(M) REP16(M) M(16) M(17) M(18) M(19)
#define REP22(M) REP20(M) M(20) M(21)

#define DECLW(n) float4 w##n;

#define LDG1(n, P, R0) w##n = make_float4(P[(R0+4*n+0)*G1_+j], P[(R0+4*n+1)*G1_+j], \
                                          P[(R0+4*n+2)*G1_+j], P[(R0+4*n+3)*G1_+j]);
#define LDG2(n, P, R0) w##n = make_float4(P[(R0+4*n+0)*G2_+j], P[(R0+4*n+1)*G2_+j], \
                                          P[(R0+4*n+2)*G2_+j], P[(R0+4*n+3)*G2_+j]);
#define LDW1(n)  LDG1(n, W1, 0)
#define LDU1(n)  LDG1(n, U1, 0)
#define LDW2A(n) LDG2(n, W2, 0)
#define LDW2B(n) LDG2(n, W2, 80)
#define LDU2(n)  LDG2(n, U2, 0)

#define DOTW(n) { float4 hv_ = hb4[n]; a0 += hv_.x*w##n.x; a1 += hv_.y*w##n.y; \
                  a2 += hv_.z*w##n.z; a3 += hv_.w*w##n.w; }

__global__ __launch_bounds__(512, 2)
void lstm_fused(
    const float* __restrict__ x,
    const float* __restrict__ W1, const float* __restrict__ U1, const float* __restrict__ b1,
    const float* __restrict__ W2, const float* __restrict__ U2, const float* __restrict__ b2,
    const float* __restrict__ Wd, const float* __restrict__ bd,
    float* __restrict__ out)
{
    __shared__ float lds[LDS_FLOATS];
    const int b = blockIdx.x;
    const int j = threadIdx.x;

    REP22(DECLW)            // w0..w21
    float c1 = 0.0f;        // cell state, thread k<100 owns c1[k]
    float c2 = 0.0f;        // cell state, thread k<128 owns c2[k]

    if (j < 128) { lds[OFF_H1S + j] = 0.0f; lds[OFF_H2S + j] = 0.0f; }
    __syncthreads();

    const float* xrow = x + (size_t)b * T_ * F_;

    for (int ch = 0; ch < NCHUNK; ++ch) {
        // ---- stage xs: TC*F_ = 2048 floats = 512 float4, 1/thread ----
        ((float4*)&lds[OFF_XS])[j] = ((const float4*)(xrow + ch * TC * F_))[j];
        // ---- W1 column j: 16 f4 (rows 0..63) ----
        if (j < G1_) { REP16(LDW1) }
        __syncthreads();   // xs staged; prev chunk's B reads of xp2 done

        // ---- A0: xp1[t][j] = b1[j] + x_t . W1col_j ----
        if (j < G1_) {
            const float bj = b1[j];
            for (int t = 0; t < TC; ++t) {
                const float4* hb4 = (const float4*)&lds[OFF_XS + t * F_];
                float a0 = bj, a1 = 0.f, a2 = 0.f, a3 = 0.f;
                REP16(DOTW)
                lds[OFF_XP1 + t * G1_ + j] = (a0 + a1) + (a2 + a3);
            }
            // U1 rows 0..79 into regs (20 f4)
            REP20(LDU1)
        }
        // ---- U1 rows 80..99 -> LDS (8000 floats = 2000 f4) ----
        {
            const float4* s4 = (const float4*)(U1 + U1_REG_ROWS * G1_);
            float4* d4 = (float4*)&lds[OFF_WLDS];
            #pragma unroll
            for (int r = 0; r < 4; ++r) {
                int idx = r * 512 + j;
                if (idx < 2000) d4[idx] = s4[idx];
            }
        }
        __syncthreads();   // xp1 + U1part ready

        // ---- A1: layer-1 recurrence ----
        for (int t = 0; t < TC; ++t) {
            if (j < G1_) {
                const float4* hb4 = (const float4*)&lds[OFF_H1S];
                float a0 = lds[OFF_XP1 + t * G1_ + j], a1 = 0.f, a2 = 0.f, a3 = 0.f;
                REP20(DOTW)                      // rows 0..79 from regs
                #pragma unroll
                for (int m = 0; m < H1_ - U1_REG_ROWS; ++m)   // rows 80..99 from LDS
                    a0 += lds[OFF_H1S + U1_REG_ROWS + m] * lds[OFF_WLDS + m * G1_ + j];
                lds[OFF_ZBUF + j] = (a0 + a1) + (a2 + a3);
            }
            __syncthreads();
            if (j < H1_) {
                float zi = lds[OFF_ZBUF + j];
                float zf = lds[OFF_ZBUF + H1_ + j];
                float zg = lds[OFF_ZBUF + 2 * H1_ + j];
                float zo = lds[OFF_ZBUF + 3 * H1_ + j];
                float ig = sigm(zi);
                float fg = sigm(zf);
                float gg = fmaxf(zg, 0.0f);
                float og = sigm(zo);
                c1 = fg * c1 + ig * gg;
                float h = og * fmaxf(c1, 0.0f);
                lds[OFF_H1S + j] = h;
                lds[OFF_H1C + t * H1_ + j] = h;
            }
            __syncthreads();
        }

        // ---- A2 pass 1: xp2[t][j] = b2[j] + h1_t[0:80] . W2[0:80,j] ----
        {
            REP20(LDW2A)
            const float bj = b2[j];
            for (int t = 0; t < TC; ++t) {
                const float4* hb4 = (const float4*)&lds[OFF_H1C + t * H1_];
                float a0 = bj, a1 = 0.f, a2 = 0.f, a3 = 0.f;
                REP20(DOTW)
                lds[OFF_XP2 + t * G2_ + j] = (a0 + a1) + (a2 + a3);
            }
        }
        // ---- A2 pass 2: xp2[t][j] += h1_t[80:100] . W2[80:100,j] (same owner, no barrier) ----
        {
            REP5(LDW2B)
            for (int t = 0; t < TC; ++t) {
                const float4* hb4 = (const float4*)&lds[OFF_H1C + t * H1_ + 80];
                float a0 = 0.f, a1 = 0.f, a2 = 0.f, a3 = 0.f;
                REP5(DOTW)
                lds[OFF_XP2 + t * G2_ + j] += (a0 + a1) + (a2 + a3);
            }
        }
        // ---- U2 rows 0..87 into regs (22 f4); rows 88..127 -> LDS (5120 f4) ----
        REP22(LDU2)
        {
            const float4* s4 = (const float4*)(U2 + U2_REG_ROWS * G2_);
            float4* d4 = (float4*)&lds[OFF_WLDS];
            #pragma unroll
            for (int r = 0; r < 10; ++r)
                d4[r * 512 + j] = s4[r * 512 + j];
        }
        __syncthreads();   // xp2 + U2part ready

        // ---- B: layer-2 recurrence ----
        for (int t = 0; t < TC; ++t) {
            {
                const float4* hb4 = (const float4*)&lds[OFF_H2S];
                float a0 = lds[OFF_XP2 + t * G2_ + j], a1 = 0.f, a2 = 0.f, a3 = 0.f;
                REP22(DOTW)                      // rows 0..87 from regs
                #pragma unroll
                for (int m = 0; m < H2_ - U2_REG_ROWS; ++m)   // rows 88..127 from LDS
                    a0 += lds[OFF_H2S + U2_REG_ROWS + m] * lds[OFF_WLDS + m * G2_ + j];
                lds[OFF_ZBUF + j] = (a0 + a1) + (a2 + a3);
            }
            __syncthreads();
            if (j < H2_) {
                float zi = lds[OFF_ZBUF + j];
                float zf = lds[OFF_ZBUF + H2_ + j];
                float zg = lds[OFF_ZBUF + 2 * H2_ + j];
                float zo = lds[OFF_ZBUF + 3 * H2_ + j];
                float ig = sigm(zi);
                float fg = sigm(zf);
                float gg = fmaxf(zg, 0.0f);
                float og = sigm(zo);
                c2 = fg * c2 + ig * gg;
                float h = og * fmaxf(c2, 0.0f);
                lds[OFF_H2S + j] = h;
            }
            __syncthreads();
        }
    }

    // ---- head: logits = h2_last @ Wd + bd ; softmax over 19 ----
    if (j < OUT_) {
        float acc = bd[j];
        #pragma unroll
        for (int k = 0; k < H2_; ++k) acc += lds[OFF_H2S + k] * Wd[k * OUT_ + j];
        lds[OFF_ZBUF + j] = acc;
    }
    __syncthreads();
    if (j < OUT_) {
        float m = -1e30f;
        for (int k = 0; k < OUT_; ++k) m = fmaxf(m, lds[OFF_ZBUF + k]);
        float s = 0.0f;
        for (int k = 0; k < OUT_; ++k) s += expf(lds[OFF_ZBUF + k] - m);
        out[b * OUT_ + j] = expf(lds[OFF_ZBUF + j] - m) / s;
    }
}

extern "C" void kernel_launch(void* const* d_in, const int* in_sizes, int n_in,
                              void* d_out, int out_size, void* d_ws, size_t ws_size,
                              hipStream_t stream) {
    const float* x  = (const float*)d_in[0];
    const float* W1 = (const float*)d_in[1];
    const float* U1 = (const float*)d_in[2];
    const float* b1 = (const float*)d_in[3];
    const float* W2 = (const float*)d_in[4];
    const float* U2 = (const float*)d_in[5];
    const float* b2 = (const float*)d_in[6];
    const float* Wd = (const float*)d_in[7];
    const float* bd = (const float*)d_in[8];
    float* out = (float*)d_out;

    hipLaunchKernelGGL(lstm_fused, dim3(B_), dim3(512), 0, stream,
                       x, W1, U1, b1, W2, U2, b2, Wd, bd, out);
}

// Round 7
// 6440.228 us; speedup vs baseline: 1.2810x; 1.2810x over previous
//
#include <hip/hip_runtime.h>
#include <math.h>

// Problem dims
#define B_   256
#define T_   512
#define F_   64
#define H1_  100
#define H2_  128
#define OUT_ 19
#define G1_  400   // 4*H1
#define G2_  512   // 4*H2
#define TC   16    // timesteps per chunk
#define NCHUNK (T_/TC)

// Row split: rows [0,72) of U1/U2 live in registers (18 f4), the rest in LDS.
#define RREG 72

// ---- LDS layout (float indices) ----
// region1 [0,8192): A-phase xs[1024]@0 + xp1[6400]@1024 ; B-phase xp2[8192]@0
#define OFF_XS    0
#define OFF_XP1   1024
#define OFF_XP2   0
#define OFF_H1C   8192                    // TC*H1_ = 1600
#define OFF_WLDS  9792                    // A1: U1 rows 72..99 (28*400=11200)
                                          // B : U2 rows 72..127 (56*512=28672)
#define OFF_ZBUF  (OFF_WLDS + 28672)      // 38464, 512
#define OFF_H1S   (OFF_ZBUF + 512)        // 38976, 128 (100 used)
#define OFF_H2S   (OFF_H1S + 128)         // 39104, 128
#define LDS_FLOATS (OFF_H2S + 128)        // 39232 fl = 156928 B (<=163840)

__device__ __forceinline__ float sigm(float x) {
    return 1.0f / (1.0f + __expf(-x));
}

// Compiler fence: bounds the number of weight loads in flight (caps the
// address-register pressure spike that caused R5/R6 spills).
#define FENCE asm volatile("" ::: "memory");

#define DECLW(n) float4 w##n;
#define REP16(M) M(0) M(1) M(2) M(3) M(4) M(5) M(6) M(7) M(8) M(9) M(10) M(11) M(12) M(13) M(14) M(15)
#define REP18(M) REP16(M) M(16) M(17)

// fenced load sequences (groups of 4 f4 = 16 scalar loads in flight max)
#define LSEQ16(M) M(0) M(1) M(2) M(3) FENCE M(4) M(5) M(6) M(7) FENCE \
                  M(8) M(9) M(10) M(11) FENCE M(12) M(13) M(14) M(15) FENCE
#define LSEQ18(M) LSEQ16(M) M(16) M(17) FENCE
#define LSEQ9(M)  M(0) M(1) M(2) M(3) FENCE M(4) M(5) M(6) M(7) FENCE M(8) FENCE

#define LDW1(n)  w##n = make_float4(W1[(4*n+0)*G1_+j], W1[(4*n+1)*G1_+j], \
                                    W1[(4*n+2)*G1_+j], W1[(4*n+3)*G1_+j]);
#define LDU1(n)  w##n = make_float4(U1[(4*n+0)*G1_+j], U1[(4*n+1)*G1_+j], \
                                    U1[(4*n+2)*G1_+j], U1[(4*n+3)*G1_+j]);
#define LDW2A(n) w##n = make_float4(W2[(4*n+0)*G2_+j], W2[(4*n+1)*G2_+j], \
                                    W2[(4*n+2)*G2_+j], W2[(4*n+3)*G2_+j]);
#define LDW2B(n) w##n = make_float4(W2[(64+4*n+0)*G2_+j], W2[(64+4*n+1)*G2_+j], \
                                    W2[(64+4*n+2)*G2_+j], W2[(64+4*n+3)*G2_+j]);
#define LDU2(n)  w##n = make_float4(U2[(4*n+0)*G2_+j], U2[(4*n+1)*G2_+j], \
                                    U2[(4*n+2)*G2_+j], U2[(4*n+3)*G2_+j]);

#define DOTW(n) { float4 hv_ = hb4[n]; a0 += hv_.x*w##n.x; a1 += hv_.y*w##n.y; \
                  a2 += hv_.z*w##n.z; a3 += hv_.w*w##n.w; }

__global__ __launch_bounds__(512, 2)
void lstm_fused(
    const float* __restrict__ x,
    const float* __restrict__ W1, const float* __restrict__ U1, const float* __restrict__ b1,
    const float* __restrict__ W2, const float* __restrict__ U2, const float* __restrict__ b2,
    const float* __restrict__ Wd, const float* __restrict__ bd,
    float* __restrict__ out)
{
    __shared__ float lds[LDS_FLOATS];
    const int b = blockIdx.x;
    const int j = threadIdx.x;

    REP18(DECLW)            // w0..w17: per-phase weight regs (max 18 f4 = 72)
    float c1 = 0.0f;        // cell state, thread k<100 owns c1[k]
    float c2 = 0.0f;        // cell state, thread k<128 owns c2[k]

    if (j < 128) { lds[OFF_H1S + j] = 0.0f; lds[OFF_H2S + j] = 0.0f; }
    __syncthreads();

    const float* xrow = x + (size_t)b * T_ * F_;

    for (int ch = 0; ch < NCHUNK; ++ch) {
        // ---- stage xs: TC*F_ = 1024 floats = 256 f4 ----
        if (j < 256)
            ((float4*)&lds[OFF_XS])[j] = ((const float4*)(xrow + ch * TC * F_))[j];
        // ---- stage WLDS = U1 rows 72..99 (11200 fl = 2800 f4) ----
        {
            const float4* s4 = (const float4*)(U1 + RREG * G1_);
            float4* d4 = (float4*)&lds[OFF_WLDS];
            #pragma unroll
            for (int r = 0; r < 6; ++r) {
                int idx = r * 512 + j;
                if (idx < 2800) d4[idx] = s4[idx];
            }
        }
        // ---- W1 col j: 16 f4 (rows 0..63), fenced groups ----
        if (j < G1_) { LSEQ16(LDW1) }
        __syncthreads();   // xs + WLDS(U1) ready; prev B's xp2/WLDS reads done

        // ---- A0: xp1[t][j] = b1[j] + x_t . W1col ----
        if (j < G1_) {
            const float bj = b1[j];
            for (int t = 0; t < TC; ++t) {
                const float4* hb4 = (const float4*)&lds[OFF_XS + t * F_];
                float a0 = bj, a1 = 0.f, a2 = 0.f, a3 = 0.f;
                REP16(DOTW)
                lds[OFF_XP1 + t * G1_ + j] = (a0 + a1) + (a2 + a3);
            }
            // U1 rows 0..71 into regs
            LSEQ18(LDU1)
        }
        __syncthreads();   // xp1 ready

        // ---- A1: layer-1 recurrence ----
        for (int t = 0; t < TC; ++t) {
            if (j < G1_) {
                const float4* hb4 = (const float4*)&lds[OFF_H1S];
                float a0 = lds[OFF_XP1 + t * G1_ + j], a1 = 0.f, a2 = 0.f, a3 = 0.f;
                REP18(DOTW)                       // rows 0..71 from regs
                #pragma unroll
                for (int m = 0; m < H1_ - RREG; m += 4) {   // rows 72..99 from LDS
                    a0 += lds[OFF_H1S + RREG + m    ] * lds[OFF_WLDS + (m    ) * G1_ + j];
                    a1 += lds[OFF_H1S + RREG + m + 1] * lds[OFF_WLDS + (m + 1) * G1_ + j];
                    a2 += lds[OFF_H1S + RREG + m + 2] * lds[OFF_WLDS + (m + 2) * G1_ + j];
                    a3 += lds[OFF_H1S + RREG + m + 3] * lds[OFF_WLDS + (m + 3) * G1_ + j];
                }
                lds[OFF_ZBUF + j] = (a0 + a1) + (a2 + a3);
            }
            __syncthreads();
            if (j < H1_) {
                float zi = lds[OFF_ZBUF + j];
                float zf = lds[OFF_ZBUF + H1_ + j];
                float zg = lds[OFF_ZBUF + 2 * H1_ + j];
                float zo = lds[OFF_ZBUF + 3 * H1_ + j];
                float ig = sigm(zi);
                float fg = sigm(zf);
                float gg = fmaxf(zg, 0.0f);
                float og = sigm(zo);
                c1 = fg * c1 + ig * gg;
                float h = og * fmaxf(c1, 0.0f);
                lds[OFF_H1S + j] = h;
                lds[OFF_H1C + t * H1_ + j] = h;
            }
            __syncthreads();
        }

        // ---- A2 pass 1: xp2[t][j] = b2[j] + h1_t[0:64] . W2[0:64,j] ----
        // (xp2 overlays xs/xp1 — both dead after A1's final barrier)
        {
            LSEQ16(LDW2A)
            const float bj = b2[j];
            for (int t = 0; t < TC; ++t) {
                const float4* hb4 = (const float4*)&lds[OFF_H1C + t * H1_];
                float a0 = bj, a1 = 0.f, a2 = 0.f, a3 = 0.f;
                REP16(DOTW)
                lds[OFF_XP2 + t * G2_ + j] = (a0 + a1) + (a2 + a3);
            }
        }
        // ---- A2 pass 2: += h1_t[64:100] . W2[64:100,j] (same owner, no barrier) ----
        {
            LSEQ9(LDW2B)
            for (int t = 0; t < TC; ++t) {
                const float4* hb4 = (const float4*)&lds[OFF_H1C + t * H1_ + 64];
                float a0 = 0.f, a1 = 0.f, a2 = 0.f, a3 = 0.f;
                DOTW(0) DOTW(1) DOTW(2) DOTW(3) DOTW(4) DOTW(5) DOTW(6) DOTW(7) DOTW(8)
                lds[OFF_XP2 + t * G2_ + j] += (a0 + a1) + (a2 + a3);
            }
        }
        // ---- U2 rows 0..71 into regs; rows 72..127 -> WLDS (28672 fl = 7168 f4) ----
        LSEQ18(LDU2)
        {
            const float4* s4 = (const float4*)(U2 + RREG * G2_);
            float4* d4 = (float4*)&lds[OFF_WLDS];
            #pragma unroll
            for (int r = 0; r < 14; ++r)
                d4[r * 512 + j] = s4[r * 512 + j];
        }
        __syncthreads();   // xp2 + WLDS(U2) ready

        // ---- B: layer-2 recurrence ----
        for (int t = 0; t < TC; ++t) {
            {
                const float4* hb4 = (const float4*)&lds[OFF_H2S];
                float a0 = lds[OFF_XP2 + t * G2_ + j], a1 = 0.f, a2 = 0.f, a3 = 0.f;
                REP18(DOTW)                       // rows 0..71 from regs
                #pragma unroll
                for (int m = 0; m < H2_ - RREG; m += 4) {   // rows 72..127 from LDS
                    a0 += lds[OFF_H2S + RREG + m    ] * lds[OFF_WLDS + (m    ) * G2_ + j];
                    a1 += lds[OFF_H2S + RREG + m + 1] * lds[OFF_WLDS + (m + 1) * G2_ + j];
                    a2 += lds[OFF_H2S + RREG + m + 2] * lds[OFF_WLDS + (m + 2) * G2_ + j];
                    a3 += lds[OFF_H2S + RREG + m + 3] * lds[OFF_WLDS + (m + 3) * G2_ + j];
                }
                lds[OFF_ZBUF + j] = (a0 + a1) + (a2 + a3);
            }
            __syncthreads();
            if (j < H2_) {
                float zi = lds[OFF_ZBUF + j];
                float zf = lds[OFF_ZBUF + H2_ + j];
                float zg = lds[OFF_ZBUF + 2 * H2_ + j];
                float zo = lds[OFF_ZBUF + 3 * H2_ + j];
                float ig = sigm(zi);
                float fg = sigm(zf);
                float gg = fmaxf(zg, 0.0f);
                float og = sigm(zo);
                c2 = fg * c2 + ig * gg;
                float h = og * fmaxf(c2, 0.0f);
                lds[OFF_H2S + j] = h;
            }
            __syncthreads();
        }
    }

    // ---- head: logits = h2_last @ Wd + bd ; softmax over 19 ----
    if (j < OUT_) {
        float acc = bd[j];
        #pragma unroll
        for (int k = 0; k < H2_; ++k) acc += lds[OFF_H2S + k] * Wd[k * OUT_ + j];
        lds[OFF_ZBUF + j] = acc;
    }
    __syncthreads();
    if (j < OUT_) {
        float m = -1e30f;
        for (int k = 0; k < OUT_; ++k) m = fmaxf(m, lds[OFF_ZBUF + k]);
        float s = 0.0f;
        for (int k = 0; k < OUT_; ++k) s += expf(lds[OFF_ZBUF + k] - m);
        out[b * OUT_ + j] = expf(lds[OFF_ZBUF + j] - m) / s;
    }
}

extern "C" void kernel_launch(void* const* d_in, const int* in_sizes, int n_in,
                              void* d_out, int out_size, void* d_ws, size_t ws_size,
                              hipStream_t stream) {
    const float* x  = (const float*)d_in[0];
    const float* W1 = (const float*)d_in[1];
    const float* U1 = (const float*)d_in[2];
    const float* b1 = (const float*)d_in[3];
    const float* W2 = (const float*)d_in[4];
    const float* U2 = (const float*)d_in[5];
    const float* b2 = (const float*)d_in[6];
    const float* Wd = (const float*)d_in[7];
    const float* bd = (const float*)d_in[8];
    float* out = (float*)d_out;

    hipLaunchKernelGGL(lstm_fused, dim3(B_), dim3(512), 0, stream,
                       x, W1, U1, b1, W2, U2, b2, Wd, bd, out);
}